// Round 2
// baseline (7302.819 us; speedup 1.0000x reference)
//
#include <hip/hip_runtime.h>

// RetinaNet 3D head: 2 heads (cls, reg) x 4 pyramid levels.
// Levels: S = 32,16,8,4 ; voxels 32768,4096,512,64 ; total 37440.
// Activation buffers: [head][level-concat][64ch][vox] fp32.
//
// Conv kernels use LDS-staged 8x8x4 tiles with 10x10x6 halo (600 floats),
// double-buffered: prefetch ci+1 into registers while FMA-ing ci from LDS.

static constexpr int TOTVOX = 37440;
static constexpr int HSTRIDE = 64 * TOTVOX;          // per-head activation elems
static constexpr int CLS_TOTAL = 18 * TOTVOX;        // 673920
static constexpr int HALO = 600;                     // 10*10*6

// sb in [0,147): l0:128 tiles, l1:16, l2:2, l3:1. Tile = 8x8x4 (x,y,z).
__device__ __forceinline__ void decompose_sb(int sb, int& lvl, int& S, int& nvox,
                                             int& loff, int& x0, int& y0, int& z0)
{
    int t;
    if (sb < 128)      { lvl = 0; t = sb; }
    else if (sb < 144) { lvl = 1; t = sb - 128; }
    else if (sb < 146) { lvl = 2; t = sb - 144; }
    else               { lvl = 3; t = 0; }
    const int ls = 5 - lvl;
    S = 1 << ls; nvox = 1 << (3 * ls);
    loff = (lvl == 0) ? 0 : (lvl == 1) ? 32768 : (lvl == 2) ? 36864 : 37376;
    const int ntx = (S >= 8) ? (S >> 3) : 1;   // tiles along x (and y)
    x0 = (t % ntx) * 8;
    const int rem = t / ntx;
    y0 = (rem % ntx) * 8;
    z0 = (rem / ntx) * 4;
}

// Precompute staging slot -> (clamped input offset, mask). 256 threads cover 600.
__device__ __forceinline__ void stage_offsets(int tid, int S, int x0, int y0, int z0,
                                              int soff[3], float smsk[3])
{
    #pragma unroll
    for (int j = 0; j < 3; ++j) {
        const int i = tid + j * 256;
        const bool inr = i < HALO;
        const int ii = inr ? i : 0;
        const int zz = ii / 100;
        const int rr = ii - zz * 100;
        const int yy = rr / 10;
        const int xx = rr - yy * 10;
        const int gx = x0 + xx - 1, gy = y0 + yy - 1, gz = z0 + zz - 1;
        const bool ok = inr && (unsigned)gx < (unsigned)S &&
                        (unsigned)gy < (unsigned)S && (unsigned)gz < (unsigned)S;
        const int cx = min(max(gx, 0), S - 1);
        const int cy = min(max(gy, 0), S - 1);
        const int cz = min(max(gz, 0), S - 1);
        soff[j] = (cz * S + cy) * S + cx;
        smsk[j] = ok ? 1.0f : 0.0f;
    }
}

// ---------------------------------------------------------------------------
// Conv3d 3x3x3 SAME + bias, fused per-channel sum/sumsq (instance-norm stats).
// Grid: x = 147 spatial tiles, y = cout chunks (NCO each), z = head.
// ---------------------------------------------------------------------------
template<int CIN, int NCO>
__global__ __launch_bounds__(256) void conv_stats_kernel(
    const float* __restrict__ q0, const float* __restrict__ q1,
    const float* __restrict__ q2, const float* __restrict__ q3,
    const float* __restrict__ src,
    const float* __restrict__ w_cls, const float* __restrict__ w_reg,
    const float* __restrict__ b_cls, const float* __restrict__ b_reg,
    float* __restrict__ dst, float* __restrict__ stats)
{
    __shared__ float lds[2][HALO];
    const int tid  = threadIdx.x;
    const int head = blockIdx.z;
    const int co0  = blockIdx.y * NCO;

    int lvl, S, nvox, loff, x0, y0, z0;
    decompose_sb(blockIdx.x, lvl, S, nvox, loff, x0, y0, z0);

    const float* in;
    if constexpr (CIN == 36) {
        in = (lvl == 0) ? q0 : (lvl == 1) ? q1 : (lvl == 2) ? q2 : q3;
    } else {
        in = src + head * HSTRIDE + loff * 64;
    }
    const float* w = head ? w_reg : w_cls;
    const float* b = head ? b_reg : b_cls;

    int soff[3]; float smsk[3];
    stage_offsets(tid, S, x0, y0, z0, soff, smsk);
    const bool ok2 = tid < (HALO - 512);

    const int tx = tid & 7, ty = (tid >> 3) & 7, tz = tid >> 6;
    const int lbase = (tz * 10 + ty) * 10 + tx;
    const int gx = x0 + tx, gy = y0 + ty, gz = z0 + tz;
    const bool valid = (gx < S) && (gy < S) && (gz < S);
    const int voxel = (gz * S + gy) * S + gx;

    float acc[NCO];
    #pragma unroll
    for (int co = 0; co < NCO; ++co) acc[co] = b[co0 + co];

    float pr0, pr1, pr2;
    auto prefetch = [&](int ci) {
        const float* ip = in + (long)ci * nvox;
        pr0 = ip[soff[0]] * smsk[0];
        pr1 = ip[soff[1]] * smsk[1];
        pr2 = ip[soff[2]] * smsk[2];
    };
    auto store_lds = [&](float* lbuf) {
        lbuf[tid] = pr0;
        lbuf[tid + 256] = pr1;
        if (ok2) lbuf[tid + 512] = pr2;
    };
    auto compute = [&](const float* lbuf, int ci) {
        float v[27];
        #pragma unroll
        for (int t = 0; t < 27; ++t)
            v[t] = lbuf[lbase + (t / 9) * 100 + ((t / 3) % 3) * 10 + (t % 3)];
        const float* wp = w + (long)(co0 * CIN + ci) * 27;
        #pragma unroll
        for (int co = 0; co < NCO; ++co) {
            #pragma unroll
            for (int t = 0; t < 27; ++t)
                acc[co] = fmaf(v[t], wp[(long)co * CIN * 27 + t], acc[co]);
        }
    };

    prefetch(0); store_lds(lds[0]); __syncthreads();
    for (int ci = 0; ci < CIN; ci += 2) {
        prefetch(ci + 1);
        compute(lds[0], ci);
        store_lds(lds[1]);
        __syncthreads();
        if (ci + 2 < CIN) prefetch(ci + 2);
        compute(lds[1], ci + 1);
        if (ci + 2 < CIN) store_lds(lds[0]);
        __syncthreads();
    }

    float* dbase = dst + head * HSTRIDE + loff * 64;
    #pragma unroll
    for (int co = 0; co < NCO; ++co) {
        float s1 = valid ? acc[co] : 0.0f;
        float s2 = valid ? acc[co] * acc[co] : 0.0f;
        #pragma unroll
        for (int off = 32; off > 0; off >>= 1) {
            s1 += __shfl_xor(s1, off, 64);
            s2 += __shfl_xor(s2, off, 64);
        }
        if ((tid & 63) == 0) {
            float* st = stats + ((head * 4 + lvl) * 64 + (co0 + co)) * 2;
            atomicAdd(st + 0, s1);
            atomicAdd(st + 1, s2);
        }
        if (valid) dbase[(co0 + co) * nvox + voxel] = acc[co];
    }
}

// ---------------------------------------------------------------------------
// InstanceNorm (affine=False) + PReLU, in-place. Grid: x=9360, y=head.
// ---------------------------------------------------------------------------
__global__ __launch_bounds__(256) void norm_prelu_kernel(
    float* __restrict__ buf, const float* __restrict__ stats,
    const float* __restrict__ a_cls, const float* __restrict__ a_reg,
    const int layer)
{
    const int head = blockIdx.y;
    const int e = blockIdx.x * 256 + (int)threadIdx.x;
    int lvl;
    if (e < 2097152)      lvl = 0;
    else if (e < 2359296) lvl = 1;
    else if (e < 2392064) lvl = 2;
    else                  lvl = 3;
    const int ce   = (lvl == 0) ? 0 : (lvl == 1) ? 2097152 : (lvl == 2) ? 2359296 : 2392064;
    const int ls3  = 3 * (5 - lvl);
    const int nvox = 1 << ls3;
    const int ch   = (e - ce) >> ls3;

    const float* st = stats + ((head * 4 + lvl) * 64 + ch) * 2;
    const float inv_n = 1.0f / (float)nvox;
    const float mean = st[0] * inv_n;
    float var = st[1] * inv_n - mean * mean;
    var = fmaxf(var, 0.0f);
    const float rstd = rsqrtf(var + 1e-5f);
    const float alpha = (head ? a_reg : a_cls)[layer];

    float* p = buf + head * HSTRIDE + e;
    const float val = (*p - mean) * rstd;
    *p = (val >= 0.0f) ? val : alpha * val;
}

// ---------------------------------------------------------------------------
// Final conv3d 64 -> OUT, channel-last output directly into d_out.
// Grid: x = 147 spatial tiles, y = cout chunks.
// ---------------------------------------------------------------------------
template<int NCO>
__global__ __launch_bounds__(256) void final_conv_kernel(
    const float* __restrict__ src, const float* __restrict__ wf,
    const float* __restrict__ bf, float* __restrict__ out, const int OUT)
{
    __shared__ float lds[2][HALO];
    const int tid = threadIdx.x;
    const int co0 = blockIdx.y * NCO;

    int lvl, S, nvox, loff, x0, y0, z0;
    decompose_sb(blockIdx.x, lvl, S, nvox, loff, x0, y0, z0);

    const float* in = src + loff * 64;

    int soff[3]; float smsk[3];
    stage_offsets(tid, S, x0, y0, z0, soff, smsk);
    const bool ok2 = tid < (HALO - 512);

    const int tx = tid & 7, ty = (tid >> 3) & 7, tz = tid >> 6;
    const int lbase = (tz * 10 + ty) * 10 + tx;
    const int gx = x0 + tx, gy = y0 + ty, gz = z0 + tz;
    const bool valid = (gx < S) && (gy < S) && (gz < S);
    const int voxel = (gz * S + gy) * S + gx;

    float acc[NCO];
    #pragma unroll
    for (int co = 0; co < NCO; ++co) acc[co] = bf[co0 + co];

    float pr0, pr1, pr2;
    auto prefetch = [&](int ci) {
        const float* ip = in + (long)ci * nvox;
        pr0 = ip[soff[0]] * smsk[0];
        pr1 = ip[soff[1]] * smsk[1];
        pr2 = ip[soff[2]] * smsk[2];
    };
    auto store_lds = [&](float* lbuf) {
        lbuf[tid] = pr0;
        lbuf[tid + 256] = pr1;
        if (ok2) lbuf[tid + 512] = pr2;
    };
    auto compute = [&](const float* lbuf, int ci) {
        float v[27];
        #pragma unroll
        for (int t = 0; t < 27; ++t)
            v[t] = lbuf[lbase + (t / 9) * 100 + ((t / 3) % 3) * 10 + (t % 3)];
        const float* wp = wf + (long)(co0 * 64 + ci) * 27;
        #pragma unroll
        for (int co = 0; co < NCO; ++co) {
            #pragma unroll
            for (int t = 0; t < 27; ++t)
                acc[co] = fmaf(v[t], wp[(long)co * 64 * 27 + t], acc[co]);
        }
    };

    prefetch(0); store_lds(lds[0]); __syncthreads();
    for (int ci = 0; ci < 64; ci += 2) {
        prefetch(ci + 1);
        compute(lds[0], ci);
        store_lds(lds[1]);
        __syncthreads();
        if (ci + 2 < 64) prefetch(ci + 2);
        compute(lds[1], ci + 1);
        if (ci + 2 < 64) store_lds(lds[0]);
        __syncthreads();
    }

    if (valid) {
        const long base = (long)(loff + voxel) * OUT;
        #pragma unroll
        for (int co = 0; co < NCO; ++co)
            out[base + co0 + co] = acc[co];
    }
}

// ---------------------------------------------------------------------------
extern "C" void kernel_launch(void* const* d_in, const int* in_sizes, int n_in,
                              void* d_out, int out_size, void* d_ws, size_t ws_size,
                              hipStream_t stream)
{
    const float* p0      = (const float*)d_in[0];
    const float* p1      = (const float*)d_in[1];
    const float* p2      = (const float*)d_in[2];
    const float* p3      = (const float*)d_in[3];
    const float* cls_w1  = (const float*)d_in[4];
    const float* cls_b1  = (const float*)d_in[5];
    const float* cls_w234= (const float*)d_in[6];
    const float* cls_b234= (const float*)d_in[7];
    const float* cls_a   = (const float*)d_in[8];
    const float* cls_wf  = (const float*)d_in[9];
    const float* cls_bf  = (const float*)d_in[10];
    const float* reg_w1  = (const float*)d_in[11];
    const float* reg_b1  = (const float*)d_in[12];
    const float* reg_w234= (const float*)d_in[13];
    const float* reg_b234= (const float*)d_in[14];
    const float* reg_a   = (const float*)d_in[15];
    const float* reg_wf  = (const float*)d_in[16];
    const float* reg_bf  = (const float*)d_in[17];

    float* ws    = (float*)d_ws;
    float* stats = ws;                 // 4 layers * 2 heads * 4 lvl * 64 ch * 2 = 4096 floats
    float* bufA  = ws + 4096;          // 2 * HSTRIDE
    float* bufB  = bufA + 2 * HSTRIDE; // 2 * HSTRIDE

    hipMemsetAsync(stats, 0, 4096 * sizeof(float), stream);

    const dim3 cgrid(147, 4, 2);   // 64 cout / 16
    const dim3 ngrid(9360, 2);

    // layer 0: 36 -> 64
    conv_stats_kernel<36, 16><<<cgrid, 256, 0, stream>>>(
        p0, p1, p2, p3, nullptr, cls_w1, reg_w1, cls_b1, reg_b1, bufA, stats);
    norm_prelu_kernel<<<ngrid, 256, 0, stream>>>(bufA, stats, cls_a, reg_a, 0);

    // layers 1..3: 64 -> 64, ping-pong A->B->A->B
    float* srcs[3] = { bufA, bufB, bufA };
    float* dsts[3] = { bufB, bufA, bufB };
    for (int l = 0; l < 3; ++l) {
        const float* wc = cls_w234 + l * 64 * 64 * 27;
        const float* wr = reg_w234 + l * 64 * 64 * 27;
        const float* bc = cls_b234 + l * 64;
        const float* br = reg_b234 + l * 64;
        float* st = stats + (l + 1) * 1024;
        conv_stats_kernel<64, 16><<<cgrid, 256, 0, stream>>>(
            nullptr, nullptr, nullptr, nullptr, srcs[l], wc, wr, bc, br, dsts[l], st);
        norm_prelu_kernel<<<ngrid, 256, 0, stream>>>(dsts[l], st, cls_a, reg_a, l + 1);
    }

    // final convs (from bufB): cls 64->18, reg 64->54, channel-last into d_out
    float* outf = (float*)d_out;
    final_conv_kernel<18><<<dim3(147, 1), 256, 0, stream>>>(bufB, cls_wf, cls_bf, outf, 18);
    final_conv_kernel<18><<<dim3(147, 3), 256, 0, stream>>>(bufB + HSTRIDE, reg_wf, reg_bf, outf + CLS_TOTAL, 54);
}

// Round 3
// 4716.884 us; speedup vs baseline: 1.5482x; 1.5482x over previous
//
#include <hip/hip_runtime.h>

// RetinaNet 3D head: 2 heads (cls, reg) x 4 pyramid levels.
// Interior levels: S = 32,16,8,4 ; voxels 32768,4096,512,64 ; total 37440.
// Activations live in ZERO-PADDED per-channel volumes (S+2)^3 so the conv
// inner loop needs no masks/clamps: taps are base + uniform (SGPR) offsets.
// Padded vols: 39304, 5832, 1000, 216 ; per-channel total 46352.

static constexpr int CLS_TOTAL  = 673920;            // 18 * 37440
static constexpr int TOTPADV    = 46352;
static constexpr size_t HSTRIDE_P = (size_t)64 * TOTPADV;   // per-head activation elems
static constexpr int PADIN_SZ   = 36 * TOTPADV;      // 1,668,672

// sb in [0,147): l0:128 tiles, l1:16, l2:2, l3:1. Tile = 8x8x4 (x,y,z) interior.
__device__ __forceinline__ void decompose(int sb, int& lvl, int& S, int& P,
                                          int& vol, int& cvol,
                                          int& x0, int& y0, int& z0)
{
    int t;
    if (sb < 128)      { lvl = 0; t = sb; }
    else if (sb < 144) { lvl = 1; t = sb - 128; }
    else if (sb < 146) { lvl = 2; t = sb - 144; }
    else               { lvl = 3; t = 0; }
    const int ls = 5 - lvl;
    S = 1 << ls; P = S + 2;
    vol  = (lvl == 0) ? 39304 : (lvl == 1) ? 5832 : (lvl == 2) ? 1000 : 216;
    cvol = (lvl == 0) ? 0     : (lvl == 1) ? 39304 : (lvl == 2) ? 45136 : 46136;
    const int ntx = (S >= 8) ? (S >> 3) : 1;
    x0 = (t % ntx) * 8;
    const int rem = t / ntx;
    y0 = (rem % ntx) * 8;
    z0 = (rem / ntx) * 4;
}

// ---------------------------------------------------------------------------
// Copy unpadded inputs p0..p3 (36 ch) into padded padin (interiors only;
// pads were zeroed by the memset).  Total 36*37440 = 1,347,840 = 5265*256.
// ---------------------------------------------------------------------------
__global__ __launch_bounds__(256) void padcopy_kernel(
    const float* __restrict__ p0, const float* __restrict__ p1,
    const float* __restrict__ p2, const float* __restrict__ p3,
    float* __restrict__ padin)
{
    const int e = blockIdx.x * 256 + (int)threadIdx.x;
    int lvl;
    if (e < 1179648)      lvl = 0;
    else if (e < 1327104) lvl = 1;
    else if (e < 1345536) lvl = 2;
    else                  lvl = 3;
    const int ce   = (lvl == 0) ? 0 : (lvl == 1) ? 1179648 : (lvl == 2) ? 1327104 : 1345536;
    const int ls   = 5 - lvl, S = 1 << ls, P = S + 2;
    const int nvox = 1 << (3 * ls);
    const int vol  = (lvl == 0) ? 39304 : (lvl == 1) ? 5832 : (lvl == 2) ? 1000 : 216;
    const int cvol = (lvl == 0) ? 0     : (lvl == 1) ? 39304 : (lvl == 2) ? 45136 : 46136;
    const int ch   = (e - ce) >> (3 * ls);
    const int vox  = (e - ce) & (nvox - 1);
    const int x = vox & (S - 1), y = (vox >> ls) & (S - 1), z = vox >> (2 * ls);
    const float* src = (lvl == 0) ? p0 : (lvl == 1) ? p1 : (lvl == 2) ? p2 : p3;
    padin[36 * cvol + ch * vol + ((z + 1) * P + (y + 1)) * P + (x + 1)] =
        src[ch * nvox + vox];
}

// ---------------------------------------------------------------------------
// Conv3d 3x3x3 SAME + bias from padded src -> padded dst, fused per-channel
// sum/sumsq (instance-norm stats).  Grid: (147, 64/NCO, 2 heads).
// Register-double-buffered tap loads; no LDS, no barriers, no masks.
// ---------------------------------------------------------------------------
template<int CIN, int NCO>
__global__ __launch_bounds__(256) void conv_pad_kernel(
    const float* __restrict__ src, const size_t head_stride,
    const float* __restrict__ w_cls, const float* __restrict__ w_reg,
    const float* __restrict__ b_cls, const float* __restrict__ b_reg,
    float* __restrict__ dst, float* __restrict__ stats)
{
    const int tid  = threadIdx.x;
    const int head = blockIdx.z;
    const int co0  = blockIdx.y * NCO;

    int lvl, S, P, vol, cvol, x0, y0, z0;
    decompose(blockIdx.x, lvl, S, P, vol, cvol, x0, y0, z0);

    const float* in = src + head * head_stride + (size_t)CIN * cvol;
    const float* w  = head ? w_reg : w_cls;
    const float* b  = head ? b_reg : b_cls;

    const int tx = tid & 7, ty = (tid >> 3) & 7, tz = tid >> 6;
    const int gx = x0 + tx, gy = y0 + ty, gz = z0 + tz;
    const bool valid = (gx < S) && (gy < S);          // only S=4 level clips
    const int cx = valid ? gx : 0, cy = valid ? gy : 0;
    const int pbase = ((gz + 1) * P + (cy + 1)) * P + (cx + 1);

    int toff[27];
    #pragma unroll
    for (int t = 0; t < 27; ++t) {
        const int dz = t / 9 - 1, dy = (t % 9) / 3 - 1, dx = t % 3 - 1;
        toff[t] = (dz * P + dy) * P + dx;             // block-uniform -> SGPR
    }

    float acc[NCO];
    #pragma unroll
    for (int co = 0; co < NCO; ++co) acc[co] = b[co0 + co];

    float va[27], vb[27];
    auto load = [&](float* v, int ci) {
        const float* ip = in + (size_t)ci * vol;
        #pragma unroll
        for (int t = 0; t < 27; ++t) v[t] = ip[pbase + toff[t]];
    };
    auto fmab = [&](const float* v, int ci) {
        const float* wp = w + (size_t)(co0 * CIN + ci) * 27;
        #pragma unroll
        for (int co = 0; co < NCO; ++co)
            #pragma unroll
            for (int t = 0; t < 27; ++t)
                acc[co] = fmaf(v[t], wp[(size_t)co * CIN * 27 + t], acc[co]);
    };

    load(va, 0);
    for (int ci = 0; ci < CIN; ci += 2) {
        load(vb, ci + 1);
        fmab(va, ci);
        if (ci + 2 < CIN) load(va, ci + 2);
        fmab(vb, ci + 1);
    }

    float* dbase = dst + head * HSTRIDE_P + (size_t)64 * cvol;
    #pragma unroll
    for (int co = 0; co < NCO; ++co) {
        float s1 = valid ? acc[co] : 0.0f;
        float s2 = valid ? acc[co] * acc[co] : 0.0f;
        #pragma unroll
        for (int off = 32; off; off >>= 1) {
            s1 += __shfl_xor(s1, off, 64);
            s2 += __shfl_xor(s2, off, 64);
        }
        if ((tid & 63) == 0) {
            float* st = stats + ((head * 4 + lvl) * 64 + co0 + co) * 2;
            atomicAdd(st + 0, s1);
            atomicAdd(st + 1, s2);
        }
        if (valid) dbase[(size_t)(co0 + co) * vol + pbase] = acc[co];
    }
}

// ---------------------------------------------------------------------------
// InstanceNorm (affine=False) + PReLU, in-place on padded buffer (interiors).
// Grid: (9360, 2).  e indexes interior elems: 64ch * 37440 vox = 2,396,160.
// ---------------------------------------------------------------------------
__global__ __launch_bounds__(256) void norm_prelu_kernel(
    float* __restrict__ buf, const float* __restrict__ stats,
    const float* __restrict__ a_cls, const float* __restrict__ a_reg,
    const int layer)
{
    const int head = blockIdx.y;
    const int e = blockIdx.x * 256 + (int)threadIdx.x;
    int lvl;
    if (e < 2097152)      lvl = 0;
    else if (e < 2359296) lvl = 1;
    else if (e < 2392064) lvl = 2;
    else                  lvl = 3;
    const int ce   = (lvl == 0) ? 0 : (lvl == 1) ? 2097152 : (lvl == 2) ? 2359296 : 2392064;
    const int ls   = 5 - lvl, S = 1 << ls, P = S + 2;
    const int nvox = 1 << (3 * ls);
    const int vol  = (lvl == 0) ? 39304 : (lvl == 1) ? 5832 : (lvl == 2) ? 1000 : 216;
    const int cvol = (lvl == 0) ? 0     : (lvl == 1) ? 39304 : (lvl == 2) ? 45136 : 46136;
    const int ch   = (e - ce) >> (3 * ls);
    const int vox  = (e - ce) & (nvox - 1);
    const int x = vox & (S - 1), y = (vox >> ls) & (S - 1), z = vox >> (2 * ls);

    const float* st = stats + ((head * 4 + lvl) * 64 + ch) * 2;
    const float inv_n = 1.0f / (float)nvox;
    const float mean = st[0] * inv_n;
    float var = st[1] * inv_n - mean * mean;
    var = fmaxf(var, 0.0f);
    const float rstd = rsqrtf(var + 1e-5f);
    const float alpha = (head ? a_reg : a_cls)[layer];

    float* p = buf + head * HSTRIDE_P + (size_t)64 * cvol + (size_t)ch * vol
                   + ((z + 1) * P + (y + 1)) * P + (x + 1);
    const float val = (*p - mean) * rstd;
    *p = (val >= 0.0f) ? val : alpha * val;
}

// ---------------------------------------------------------------------------
// Final conv3d 64 -> {18 cls | 54 reg}, both heads in one grid, channel-last
// output directly into d_out.  Grid: (147, 12) ; y<3 -> cls, else reg.
// ---------------------------------------------------------------------------
__global__ __launch_bounds__(256) void final_conv_kernel(
    const float* __restrict__ src,
    const float* __restrict__ wf_cls, const float* __restrict__ bf_cls,
    const float* __restrict__ wf_reg, const float* __restrict__ bf_reg,
    float* __restrict__ out)
{
    constexpr int NCO = 6;
    const int tid  = threadIdx.x;
    const int yb   = blockIdx.y;
    const int head = (yb >= 3) ? 1 : 0;
    const int co0  = (head ? (yb - 3) : yb) * NCO;
    const int OUT  = head ? 54 : 18;
    const float* wf = head ? wf_reg : wf_cls;
    const float* bf = head ? bf_reg : bf_cls;
    float* ob = out + (head ? CLS_TOTAL : 0);

    int lvl, S, P, vol, cvol, x0, y0, z0;
    decompose(blockIdx.x, lvl, S, P, vol, cvol, x0, y0, z0);
    const int loff = (lvl == 0) ? 0 : (lvl == 1) ? 32768 : (lvl == 2) ? 36864 : 37376;

    const float* in = src + head * HSTRIDE_P + (size_t)64 * cvol;

    const int tx = tid & 7, ty = (tid >> 3) & 7, tz = tid >> 6;
    const int gx = x0 + tx, gy = y0 + ty, gz = z0 + tz;
    const bool valid = (gx < S) && (gy < S);
    const int cx = valid ? gx : 0, cy = valid ? gy : 0;
    const int pbase = ((gz + 1) * P + (cy + 1)) * P + (cx + 1);

    int toff[27];
    #pragma unroll
    for (int t = 0; t < 27; ++t) {
        const int dz = t / 9 - 1, dy = (t % 9) / 3 - 1, dx = t % 3 - 1;
        toff[t] = (dz * P + dy) * P + dx;
    }

    float acc[NCO];
    #pragma unroll
    for (int co = 0; co < NCO; ++co) acc[co] = bf[co0 + co];

    float va[27], vb[27];
    auto load = [&](float* v, int ci) {
        const float* ip = in + (size_t)ci * vol;
        #pragma unroll
        for (int t = 0; t < 27; ++t) v[t] = ip[pbase + toff[t]];
    };
    auto fmab = [&](const float* v, int ci) {
        const float* wp = wf + (size_t)(co0 * 64 + ci) * 27;
        #pragma unroll
        for (int co = 0; co < NCO; ++co)
            #pragma unroll
            for (int t = 0; t < 27; ++t)
                acc[co] = fmaf(v[t], wp[(size_t)co * 64 * 27 + t], acc[co]);
    };

    load(va, 0);
    for (int ci = 0; ci < 64; ci += 2) {
        load(vb, ci + 1);
        fmab(va, ci);
        if (ci + 2 < 64) load(va, ci + 2);
        fmab(vb, ci + 1);
    }

    if (valid) {
        const int voxel = (gz * S + gy) * S + gx;
        float* o = ob + (size_t)(loff + voxel) * OUT + co0;
        #pragma unroll
        for (int co = 0; co < NCO; ++co) o[co] = acc[co];
    }
}

// ---------------------------------------------------------------------------
extern "C" void kernel_launch(void* const* d_in, const int* in_sizes, int n_in,
                              void* d_out, int out_size, void* d_ws, size_t ws_size,
                              hipStream_t stream)
{
    const float* p0      = (const float*)d_in[0];
    const float* p1      = (const float*)d_in[1];
    const float* p2      = (const float*)d_in[2];
    const float* p3      = (const float*)d_in[3];
    const float* cls_w1  = (const float*)d_in[4];
    const float* cls_b1  = (const float*)d_in[5];
    const float* cls_w234= (const float*)d_in[6];
    const float* cls_b234= (const float*)d_in[7];
    const float* cls_a   = (const float*)d_in[8];
    const float* cls_wf  = (const float*)d_in[9];
    const float* cls_bf  = (const float*)d_in[10];
    const float* reg_w1  = (const float*)d_in[11];
    const float* reg_b1  = (const float*)d_in[12];
    const float* reg_w234= (const float*)d_in[13];
    const float* reg_b234= (const float*)d_in[14];
    const float* reg_a   = (const float*)d_in[15];
    const float* reg_wf  = (const float*)d_in[16];
    const float* reg_bf  = (const float*)d_in[17];

    float* ws    = (float*)d_ws;
    float* stats = ws;                        // 4096 floats (4 layers x 1024)
    float* padin = ws + 4096;                 // PADIN_SZ
    float* bufA  = padin + PADIN_SZ;          // 2 * HSTRIDE_P
    float* bufB  = bufA + 2 * HSTRIDE_P;      // 2 * HSTRIDE_P

    const size_t total_f = 4096 + (size_t)PADIN_SZ + 4 * HSTRIDE_P;
    hipMemsetAsync(ws, 0, total_f * sizeof(float), stream);

    padcopy_kernel<<<5265, 256, 0, stream>>>(p0, p1, p2, p3, padin);

    const dim3 cgrid(147, 8, 2);   // NCO=8
    const dim3 ngrid(9360, 2);

    // layer 0: 36 -> 64 (padin shared by both heads: head_stride = 0)
    conv_pad_kernel<36, 8><<<cgrid, 256, 0, stream>>>(
        padin, 0, cls_w1, reg_w1, cls_b1, reg_b1, bufA, stats);
    norm_prelu_kernel<<<ngrid, 256, 0, stream>>>(bufA, stats, cls_a, reg_a, 0);

    // layers 1..3: 64 -> 64, ping-pong A->B->A->B
    float* srcs[3] = { bufA, bufB, bufA };
    float* dsts[3] = { bufB, bufA, bufB };
    for (int l = 0; l < 3; ++l) {
        const float* wc = cls_w234 + (size_t)l * 64 * 64 * 27;
        const float* wr = reg_w234 + (size_t)l * 64 * 64 * 27;
        const float* bc = cls_b234 + l * 64;
        const float* br = reg_b234 + l * 64;
        float* st = stats + (l + 1) * 1024;
        conv_pad_kernel<64, 8><<<cgrid, 256, 0, stream>>>(
            srcs[l], HSTRIDE_P, wc, wr, bc, br, dsts[l], st);
        norm_prelu_kernel<<<ngrid, 256, 0, stream>>>(dsts[l], st, cls_a, reg_a, l + 1);
    }

    // final convs from bufB: both heads in one launch, channel-last into d_out
    final_conv_kernel<<<dim3(147, 12), 256, 0, stream>>>(
        bufB, cls_wf, cls_bf, reg_wf, reg_bf, (float*)d_out);
}